// Round 11
// baseline (1691.152 us; speedup 1.0000x reference)
//
#include <hip/hip_runtime.h>
#include <math.h>
#include <stdint.h>

namespace {
constexpr int N_    = 2048;
constexpr int H_    = 800;
constexpr int IN_   = 28;
constexpr int TENC  = 28;
constexpr int TTOT  = 78;             // 28 encode + 50 decode
constexpr int ONUM  = 10;
constexpr int PODS  = 8;              // independent 256-sample pods
constexpr int PBLK  = 26;             // 25 hidden tiles + 1 output block per pod
constexpr int NBLK  = PODS * PBLK;    // 208
constexpr int NTILE = 26;             // spike strips: 25 real tiles + 1 zero K-pad
constexpr int FSTR  = 32;             // flag dwords per pod (26 used -> 2 lines)
constexpr int NSEG  = 13 * 4 * 2;     // (c, digit k, neuron-half) B segments
constexpr int SMEM_B = NSEG * 1024;          // 106496: fragment-ordered digit planes
constexpr int SMEM_W = IN_ * 32 * 4;         // 3584: Wi tile
constexpr int AROW  = 27;                    // LDS A-strip row stride (dwords)
constexpr int SMEM_A = 8 * 32 * AROW * 4;    // 27648: per-wave A strips
constexpr int SMEM_TOT = SMEM_B + SMEM_W + SMEM_A;  // 137728 <= 160K -> 1 blk/CU
}

typedef __attribute__((ext_vector_type(4))) int v4i;

// balanced base-256 digits of round(w * 2^32); exact for |w| < ~0.49
__device__ __forceinline__ void digitize(float w, int8_t d[4]) {
    double dd = (double)w * 4294967296.0;
    long long r = (long long)rint(dd);
    int8_t d0 = (int8_t)(r & 255); r = (r - (long long)d0) >> 8;
    int8_t d1 = (int8_t)(r & 255); r = (r - (long long)d1) >> 8;
    int8_t d2 = (int8_t)(r & 255); r = (r - (long long)d2) >> 8;
    long long r3 = r; r3 = r3 > 127 ? 127 : (r3 < -128 ? -128 : r3);
    d[0] = d0; d[1] = d1; d[2] = d2; d[3] = (int8_t)r3;
}

// expand 16 spike bits -> 16 bytes (0/1) as v4i
__device__ __forceinline__ v4i unpack16(uint32_t u) {
    v4i f;
    f[0] = (int)((((u      ) & 0xFu) * 0x00204081u) & 0x01010101u);
    f[1] = (int)((((u >>  4) & 0xFu) * 0x00204081u) & 0x01010101u);
    f[2] = (int)((((u >>  8) & 0xFu) * 0x00204081u) & 0x01010101u);
    f[3] = (int)((((u >> 12) & 0xFu) * 0x00204081u) & 0x01010101u);
    return f;
}

// ---- pod-local grid barrier + CONSUMER-SIDE ACQUIRE FENCE -----------------
// Producers: sc1 stores (write-through MALL) + vmcnt drain + agent flag.
// After detect, wave 0 executes ONE agent-scope acquire fence -> buffer_inv
// (invalidates this XCD's L1/L2 stale lines). Subsequent spike loads are
// WORKGROUP-scope (cacheable): first reader per line per XCD fetches from
// MALL (fresh: all producers drained before their flags), the rest hit L2.
// Flags themselves stay agent-scope both sides -> barrier liveness unchanged.
__device__ __forceinline__ void pod_barrier(uint32_t* __restrict__ flags,
                                            int pod, int l, uint32_t epoch) {
    __syncthreads();
    if (threadIdx.x < 64) {
        if (threadIdx.x == 0) {
            asm volatile("s_waitcnt vmcnt(0)" ::: "memory");
            __hip_atomic_store(flags + pod * FSTR + l, epoch,
                               __ATOMIC_RELAXED, __HIP_MEMORY_SCOPE_AGENT);
        }
        const bool mine = (threadIdx.x < PBLK);
        bool done = false;
        int itc = 0;
        while (!done) {
            bool ok = true;
            if (mine)
                ok = (__hip_atomic_load(flags + pod * FSTR + threadIdx.x,
                        __ATOMIC_RELAXED, __HIP_MEMORY_SCOPE_AGENT) >= epoch);
            done = (__ballot(ok) == ~0ull);
            if (!done) {
                if (itc < 4) __builtin_amdgcn_s_sleep(1);
                else         __builtin_amdgcn_s_sleep(8);
                ++itc;
            }
        }
        // invalidate stale L1/L2 lines so cached spike loads refetch fresh
        __builtin_amdgcn_fence(__ATOMIC_ACQUIRE, "agent");
        __builtin_amdgcn_sched_barrier(0);
    }
    __syncthreads();
}

// ---------------------------------------------------------------------------
// prepass: transpose x into xt2[t][n][c], zero tile-major spike buffers+flags
// ---------------------------------------------------------------------------
__global__ void prep_kernel(const float* __restrict__ x, float* __restrict__ xt2,
                            uint32_t* __restrict__ sp0, uint32_t* __restrict__ sp1,
                            uint32_t* __restrict__ flags)
{
    size_t idx = (size_t)blockIdx.x * blockDim.x + threadIdx.x;
    size_t stride = (size_t)gridDim.x * blockDim.x;
    const size_t TOT = (size_t)TENC * N_ * IN_;
    for (size_t e = idx; e < TOT; e += stride) {
        int t = (int)(e / (N_ * IN_));
        int rem = (int)(e % (N_ * IN_));
        int n = rem / IN_, c = rem % IN_;
        xt2[e] = x[(size_t)n * 784 + c * TENC + t];
    }
    const size_t PW = (size_t)NTILE * N_;
    for (size_t e = idx; e < PW; e += stride) { sp0[e] = 0u; sp1[e] = 0u; }
    for (size_t e = idx; e < (size_t)PODS * FSTR; e += stride) flags[e] = 0u;
}

// ---------------------------------------------------------------------------
// Persistent LSNN, pod-local sync, TILE-MAJOR spike exchange, L2-CACHED reads:
//   sp[strip][n], strips 0..24 real; strip 25 never loaded (LDS K-pad zeroed
//   once). Staging loads are WORKGROUP-scope (L2-cacheable; coherence by the
//   barrier's acquire fence). Load order rotated by block id to spread the
//   per-line first-miss. Stores: 16 lanes x 8B sc1 qwords (proven round 10).
// ---------------------------------------------------------------------------
__global__ __launch_bounds__(512)
__attribute__((amdgpu_waves_per_eu(2)))
void lsnn_persist(const float* __restrict__ xt2,
                  const float* __restrict__ Wi,
                  const float* __restrict__ b_i2h,
                  const float* __restrict__ Wh,
                  const float* __restrict__ b_h2h,
                  const float* __restrict__ Wo,
                  const float* __restrict__ b_h2o,
                  const float* __restrict__ tau_h,
                  const float* __restrict__ tau_o,
                  uint32_t* sp0, uint32_t* sp1,
                  uint32_t* flags,
                  float* __restrict__ out)
{
    extern __shared__ __align__(16) int8_t smem[];
    int8_t*   Bl  = smem;                                   // [NSEG][64][16]
    float*    wl  = (float*)(smem + SMEM_B);                // [28][32]
    uint32_t* Alds = (uint32_t*)(smem + SMEM_B + SMEM_W);   // [8 waves][32][AROW]

    const int bid  = blockIdx.x;
    const int pod  = bid / PBLK;          // 0..7 (sample group)
    const int l    = bid % PBLK;          // 0..25 (25 = o-block)
    const bool is_o = (l == 25);
    const int it   = is_o ? 0 : l;
    const int i0   = it * 32;
    const int wv   = threadIdx.x >> 6;
    const int lane = threadIdx.x & 63;
    const int quad = lane >> 4;
    const int col  = lane & 15;
    const int n0   = pod * 256 + wv * 32;
    uint32_t* ldsA = Alds + wv * 32 * AROW;
    const int dsel = (quad >> 1);
    const int dsh  = (quad & 1) * 16;

    // ---- build B digit fragments in LDS (once) ----
    for (int e = threadIdx.x; e < 13 * 2 * 64; e += 512) {
        int c  = e >> 7;
        int bh = (e >> 6) & 1;
        int ln = e & 63;
        int q  = ln >> 4, cl = ln & 15;
        int kbase = c * 64 + q * 16;
        uint32_t w4[4][4] = {};
        int row = bh * 16 + cl;
        #pragma unroll
        for (int j = 0; j < 16; ++j) {
            int kidx = kbase + j;
            float w = 0.f;
            if (kidx < H_) {
                if (!is_o) w = Wh[(size_t)(i0 + row) * H_ + kidx];
                else if (bh == 0 && cl < ONUM) w = Wo[(size_t)cl * H_ + kidx];
            }
            int8_t d[4]; digitize(w, d);
            #pragma unroll
            for (int k = 0; k < 4; ++k)
                w4[k][j >> 2] |= ((uint32_t)(uint8_t)d[k]) << ((j & 3) * 8);
        }
        #pragma unroll
        for (int k = 0; k < 4; ++k) {
            v4i v; v[0] = (int)w4[k][0]; v[1] = (int)w4[k][1];
            v[2] = (int)w4[k][2]; v[3] = (int)w4[k][3];
            *(v4i*)(Bl + (((c * 8) + k * 2 + bh) << 10) + (ln << 4)) = v;
        }
    }
    if (!is_o) {
        for (int e = threadIdx.x; e < IN_ * 32; e += 512) {
            int c = e >> 5, il = e & 31;
            wl[c * 32 + il] = Wi[(size_t)(i0 + il) * IN_ + c];
        }
    }
    // zero this wave's permanent K-pad column (strip 25 cells), written nowhere else
    if (lane >= 32) ldsA[(lane & 31) * AROW + 25] = 0u;

    // ---- constants & register state ----
    const float alpha = (float)exp((double)(-1.0f / 20.0f));
    const float onem  = 1.0f - alpha;
    const double INV32 = 1.0 / 4294967296.0;

    float roB[2] = {}, biB[2] = {}, bhB[2] = {};
    float hm[2][2][4] = {}, hbv[2][2][4];
    float om[2][4] = {}, ospv[2][4] = {}, obb[2][4], cnt[2][4] = {};
    float roO = 0.f, boO = 0.f;
    uint32_t pmask = 0;   // prev spikes for this lane's 16 outputs

    if (!is_o) {
        #pragma unroll
        for (int b = 0; b < 2; ++b) {
            int i = i0 + b * 16 + col;
            float arg = -1.0f / tau_h[i];
            roB[b] = (float)exp((double)arg);
            biB[b] = b_i2h[i]; bhB[b] = b_h2h[i];
        }
        #pragma unroll
        for (int a = 0; a < 2; ++a)
            #pragma unroll
            for (int b = 0; b < 2; ++b)
                #pragma unroll
                for (int r = 0; r < 4; ++r) hbv[a][b][r] = 0.01f;
    } else {
        if (col < ONUM) {
            float arg = -1.0f / tau_o[col];
            roO = (float)exp((double)arg);
            boO = b_h2o[col];
        }
        #pragma unroll
        for (int a = 0; a < 2; ++a)
            #pragma unroll
            for (int r = 0; r < 4; ++r) obb[a][r] = 0.01f;
    }

    // ---- per-lane staging geometry (constant across time) ----
    // pairs 0..11 (strips 0..23) rotated by block id to spread first-miss;
    // k=12 handles strip 24 (lanes<32 only; strip 25 is the permanent pad).
    uint32_t goff[13]; int loffv[13];
    #pragma unroll
    for (int k = 0; k < 13; ++k) {
        int pr   = (k < 12) ? ((k + l) % 12) : 12;
        int tile = 2 * pr + (lane >> 5);
        goff[k]  = (uint32_t)(tile * N_ + n0 + (lane & 31));
        loffv[k] = (lane & 31) * AROW + tile;
    }
    // qword spike-store gather: lane p<16 stores rows 2p,2p+1.
    const int j0 = (lane & 15) * 2;
    const int j1 = j0 + 1;
    const int s0 = ((j0 >> 2) & 3) * 16 + ((j0 >> 4) << 2) + (j0 & 3);
    const int s1 = ((j1 >> 2) & 3) * 16 + ((j1 >> 4) << 2) + (j1 & 3);

    __syncthreads();
    uint32_t epoch = 1;

    // ---- time loop ----
    for (int t = 0; t <= TTOT; ++t) {
        const uint32_t* rdP = (t & 1) ? sp1 : sp0;
        uint32_t*       wrP = (t & 1) ? sp0 : sp1;

        const bool active = is_o ? (t >= 1) : (t < TTOT);

        // ---- issue staged loads into registers (L2-cacheable, post-fence) ----
        uint32_t vv[13];
        if (active) {
            #pragma unroll
            for (int k = 0; k < 13; ++k) {
                const bool real = (k < 12) || (lane < 32);
                vv[k] = real ? __hip_atomic_load(rdP + goff[k],
                            __ATOMIC_RELAXED, __HIP_MEMORY_SCOPE_WORKGROUP) : 0u;
            }
        }

        // ---- input projection (spike-independent): overlaps load latency ----
        float inpf[2][2][4] = {};
        if (!is_o && active && t < TENC) {
            #pragma unroll
            for (int a = 0; a < 2; ++a) {
                #pragma unroll
                for (int r = 0; r < 4; ++r) {
                    int n = n0 + a * 16 + quad * 4 + r;
                    const float* xp = xt2 + ((size_t)t * N_ + n) * IN_;
                    double s0d = 0.0, s1d = 0.0;
                    #pragma unroll
                    for (int c = 0; c < IN_; ++c) {
                        double xv = (double)xp[c];
                        s0d += xv * (double)wl[c * 32 + col];
                        s1d += xv * (double)wl[c * 32 + 16 + col];
                    }
                    inpf[a][0][r] = (float)s0d;
                    inpf[a][1][r] = (float)s1d;
                }
            }
        }

        // ---- land staged words in this wave's A strip ----
        if (active) {
            #pragma unroll
            for (int k = 0; k < 13; ++k) {
                const bool real = (k < 12) || (lane < 32);
                if (real) ldsA[loffv[k]] = vv[k];
            }
        }

        if (!is_o && active) {
            v4i acc4[2][2][4] = {};
            #pragma unroll
            for (int c = 0; c < 13; ++c) {
                uint32_t d0 = ldsA[col * AROW + c * 2 + dsel];
                uint32_t d1 = ldsA[(16 + col) * AROW + c * 2 + dsel];
                v4i a0 = unpack16((d0 >> dsh) & 0xFFFFu);
                v4i a1 = unpack16((d1 >> dsh) & 0xFFFFu);
                #pragma unroll
                for (int k = 0; k < 4; ++k) {
                    v4i b0 = *(const v4i*)(Bl + (((c * 8) + k * 2 + 0) << 10) + (lane << 4));
                    v4i b1 = *(const v4i*)(Bl + (((c * 8) + k * 2 + 1) << 10) + (lane << 4));
                    acc4[0][0][k] = __builtin_amdgcn_mfma_i32_16x16x64_i8(a0, b0, acc4[0][0][k], 0, 0, 0);
                    acc4[0][1][k] = __builtin_amdgcn_mfma_i32_16x16x64_i8(a0, b1, acc4[0][1][k], 0, 0, 0);
                    acc4[1][0][k] = __builtin_amdgcn_mfma_i32_16x16x64_i8(a1, b0, acc4[1][0][k], 0, 0, 0);
                    acc4[1][1][k] = __builtin_amdgcn_mfma_i32_16x16x64_i8(a1, b1, acc4[1][1][k], 0, 0, 0);
                }
            }

            // hidden epilogue: fp32, reference order, no FMA; state in registers
            uint32_t nmask = 0;
            {
                #pragma clang fp contract(off)
                #pragma unroll
                for (int a = 0; a < 2; ++a) {
                    #pragma unroll
                    for (int b = 0; b < 2; ++b) {
                        #pragma unroll
                        for (int r = 0; r < 4; ++r) {
                            int sidx = ((a * 2 + b) * 4 + r);
                            int64_t tot = ((int64_t)acc4[a][b][3][r] << 24)
                                        + ((int64_t)acc4[a][b][2][r] << 16)
                                        + ((int64_t)acc4[a][b][1][r] << 8)
                                        +  (int64_t)acc4[a][b][0][r];
                            float rec = (float)((double)tot * INV32);
                            float h_in = ((inpf[a][b][r] + biB[b]) + rec) + bhB[b];
                            float sp = (pmask >> sidx) & 1u ? 1.0f : 0.0f;
                            float ro = roB[b];
                            float bnew = (ro * hbv[a][b][r]) + ((1.0f - ro) * sp);
                            float B = 0.01f + (1.8f * bnew);
                            float mem = ((hm[a][b][r] * alpha) + (onem * h_in)) - (B * sp);
                            float s = (mem - B) > 0.f ? 1.f : 0.f;
                            hbv[a][b][r] = bnew; hm[a][b][r] = mem;
                            if (s > 0.5f) nmask |= (1u << sidx);
                        }
                    }
                }
            }
            pmask = nmask;

            // pack spikes: ballots -> holder lanes; gather rows 2p,2p+1 into
            // lane p<16; ONE contiguous 128B segment as 16 x 8B sc1 stores.
            uint32_t wmine = 0;
            #pragma unroll
            for (int a = 0; a < 2; ++a) {
                #pragma unroll
                for (int r = 0; r < 4; ++r) {
                    unsigned long long bal0 = __ballot((nmask >> (a * 8 + r)) & 1u);
                    unsigned long long bal1 = __ballot((nmask >> (a * 8 + 4 + r)) & 1u);
                    if (col == a * 4 + r) {
                        wmine = (uint32_t)((bal0 >> (quad * 16)) & 0xFFFFull)
                              | ((uint32_t)((bal1 >> (quad * 16)) & 0xFFFFull) << 16);
                    }
                }
            }
            {
                uint32_t g0 = (uint32_t)__shfl((int)wmine, s0, 64);
                uint32_t g1 = (uint32_t)__shfl((int)wmine, s1, 64);
                if (lane < 16) {
                    uint64_t q = (uint64_t)g0 | ((uint64_t)g1 << 32);
                    uint64_t* qp = (uint64_t*)(wrP + (size_t)it * N_ + n0);
                    __hip_atomic_store(qp + (lane & 15), q,
                                       __ATOMIC_RELAXED, __HIP_MEMORY_SCOPE_AGENT);
                }
            }
        }

        if (is_o && active) {
            v4i oacc[2][4] = {};
            #pragma unroll
            for (int c = 0; c < 13; ++c) {
                uint32_t d0 = ldsA[col * AROW + c * 2 + dsel];
                uint32_t d1 = ldsA[(16 + col) * AROW + c * 2 + dsel];
                v4i a0 = unpack16((d0 >> dsh) & 0xFFFFu);
                v4i a1 = unpack16((d1 >> dsh) & 0xFFFFu);
                #pragma unroll
                for (int k = 0; k < 4; ++k) {
                    v4i bo = *(const v4i*)(Bl + (((c * 8) + k * 2 + 0) << 10) + (lane << 4));
                    oacc[0][k] = __builtin_amdgcn_mfma_i32_16x16x64_i8(a0, bo, oacc[0][k], 0, 0, 0);
                    oacc[1][k] = __builtin_amdgcn_mfma_i32_16x16x64_i8(a1, bo, oacc[1][k], 0, 0, 0);
                }
            }
            if (col < ONUM) {
                #pragma clang fp contract(off)
                const bool msk = (t - 1) >= TENC;
                #pragma unroll
                for (int a = 0; a < 2; ++a) {
                    #pragma unroll
                    for (int r = 0; r < 4; ++r) {
                        int64_t tot = ((int64_t)oacc[a][3][r] << 24)
                                    + ((int64_t)oacc[a][2][r] << 16)
                                    + ((int64_t)oacc[a][1][r] << 8)
                                    +  (int64_t)oacc[a][0][r];
                        float o_in = ((float)((double)tot * INV32)) + boO;
                        float osp_ = ospv[a][r];
                        float bnew = (roO * obb[a][r]) + ((1.0f - roO) * osp_);
                        float B = 0.01f + (1.8f * bnew);
                        float mem = ((om[a][r] * alpha) + (onem * o_in)) - (B * osp_);
                        float s = (mem - B) > 0.f ? 1.f : 0.f;
                        obb[a][r] = bnew; om[a][r] = mem; ospv[a][r] = s;
                        if (msk) cnt[a][r] += s;
                    }
                }
            }
        }

        if (t < TTOT) pod_barrier(flags, pod, l, epoch++);
    }

    // ---- write spike counts ----
    if (is_o && col < ONUM) {
        #pragma unroll
        for (int a = 0; a < 2; ++a)
            #pragma unroll
            for (int r = 0; r < 4; ++r) {
                int n = n0 + a * 16 + quad * 4 + r;
                out[(size_t)n * ONUM + col] = cnt[a][r];
            }
    }
}

// ---------------------------------------------------------------------------
extern "C" void kernel_launch(void* const* d_in, const int* in_sizes, int n_in,
                              void* d_out, int out_size, void* d_ws, size_t ws_size,
                              hipStream_t stream)
{
    const float* x      = (const float*)d_in[0];
    const float* Wi     = (const float*)d_in[1];
    const float* b_i2h  = (const float*)d_in[2];
    const float* Wh     = (const float*)d_in[3];
    const float* b_h2h  = (const float*)d_in[4];
    const float* Wo     = (const float*)d_in[5];
    const float* b_h2o  = (const float*)d_in[6];
    const float* tau_h  = (const float*)d_in[7];
    const float* tau_o  = (const float*)d_in[8];
    float* out = (float*)d_out;

    uintptr_t p = (uintptr_t)d_ws;
    auto alloc = [&](size_t bytes) -> void* {
        p = (p + 255) & ~(uintptr_t)255;
        void* r = (void*)p; p += bytes; return r;
    };
    uint32_t* sp0   = (uint32_t*)alloc((size_t)NTILE * N_ * 4);
    uint32_t* sp1   = (uint32_t*)alloc((size_t)NTILE * N_ * 4);
    float*    xt2   = (float*)alloc((size_t)TENC * N_ * IN_ * 4);
    uint32_t* flags = (uint32_t*)alloc((size_t)PODS * FSTR * 4);

    prep_kernel<<<1024, 256, 0, stream>>>(x, xt2, sp0, sp1, flags);

    (void)hipFuncSetAttribute((const void*)lsnn_persist,
                              hipFuncAttributeMaxDynamicSharedMemorySize, SMEM_TOT);
    lsnn_persist<<<NBLK, 512, SMEM_TOT, stream>>>(
        xt2, Wi, b_i2h, Wh, b_h2h, Wo, b_h2o, tau_h, tau_o,
        sp0, sp1, flags, out);
}

// Round 12
// 1399.274 us; speedup vs baseline: 1.2086x; 1.2086x over previous
//
#include <hip/hip_runtime.h>
#include <math.h>
#include <stdint.h>

namespace {
constexpr int N_    = 2048;
constexpr int H_    = 800;
constexpr int IN_   = 28;
constexpr int TENC  = 28;
constexpr int TTOT  = 78;             // 28 encode + 50 decode
constexpr int ONUM  = 10;
constexpr int PODS  = 8;              // independent 256-sample pods
constexpr int PBLK  = 26;             // 25 hidden tiles + 1 output block per pod
constexpr int NBLK  = PODS * PBLK;    // 208
constexpr int NTILE = 26;             // spike strips: 25 real tiles + 1 zero K-pad
constexpr int FSTR  = 32;             // flag dwords per pod (26 used -> 2 lines)
constexpr int NSEG  = 13 * 4 * 2;     // (c, digit k, neuron-half) B segments
constexpr int SMEM_B = NSEG * 1024;          // 106496: fragment-ordered digit planes
constexpr int SMEM_W = IN_ * 32 * 4;         // 3584: Wi tile
constexpr int AROW  = 27;                    // LDS A-strip row stride (dwords)
constexpr int SMEM_A = 8 * 32 * AROW * 4;    // 27648: per-wave A strips
constexpr int SMEM_TOT = SMEM_B + SMEM_W + SMEM_A;  // 137728 <= 160K -> 1 blk/CU
}

typedef __attribute__((ext_vector_type(4))) int v4i;

// balanced base-256 digits of round(w * 2^32); exact for |w| < ~0.49
__device__ __forceinline__ void digitize(float w, int8_t d[4]) {
    double dd = (double)w * 4294967296.0;
    long long r = (long long)rint(dd);
    int8_t d0 = (int8_t)(r & 255); r = (r - (long long)d0) >> 8;
    int8_t d1 = (int8_t)(r & 255); r = (r - (long long)d1) >> 8;
    int8_t d2 = (int8_t)(r & 255); r = (r - (long long)d2) >> 8;
    long long r3 = r; r3 = r3 > 127 ? 127 : (r3 < -128 ? -128 : r3);
    d[0] = d0; d[1] = d1; d[2] = d2; d[3] = (int8_t)r3;
}

// expand 16 spike bits -> 16 bytes (0/1) as v4i
__device__ __forceinline__ v4i unpack16(uint32_t u) {
    v4i f;
    f[0] = (int)((((u      ) & 0xFu) * 0x00204081u) & 0x01010101u);
    f[1] = (int)((((u >>  4) & 0xFu) * 0x00204081u) & 0x01010101u);
    f[2] = (int)((((u >>  8) & 0xFu) * 0x00204081u) & 0x01010101u);
    f[3] = (int)((((u >> 12) & 0xFu) * 0x00204081u) & 0x01010101u);
    return f;
}

// ---- pod-local grid barrier: 26 blocks, packed flag lines (2/pod) ---------
__device__ __forceinline__ void pod_barrier(uint32_t* __restrict__ flags,
                                            int pod, int l, uint32_t epoch) {
    __syncthreads();
    if (threadIdx.x < 64) {
        if (threadIdx.x == 0) {
            asm volatile("s_waitcnt vmcnt(0)" ::: "memory");
            __hip_atomic_store(flags + pod * FSTR + l, epoch,
                               __ATOMIC_RELAXED, __HIP_MEMORY_SCOPE_AGENT);
        }
        const bool mine = (threadIdx.x < PBLK);
        bool done = false;
        int itc = 0;
        while (!done) {
            bool ok = true;
            if (mine)
                ok = (__hip_atomic_load(flags + pod * FSTR + threadIdx.x,
                        __ATOMIC_RELAXED, __HIP_MEMORY_SCOPE_AGENT) >= epoch);
            done = (__ballot(ok) == ~0ull);
            if (!done) {
                if (itc < 4) __builtin_amdgcn_s_sleep(1);
                else         __builtin_amdgcn_s_sleep(8);
                ++itc;
            }
        }
    }
    __syncthreads();
}

// ---------------------------------------------------------------------------
// prepass: transpose x into xt2[t][n][c], zero tile-major spike buffers+flags
// ---------------------------------------------------------------------------
__global__ void prep_kernel(const float* __restrict__ x, float* __restrict__ xt2,
                            uint32_t* __restrict__ sp0, uint32_t* __restrict__ sp1,
                            uint32_t* __restrict__ flags)
{
    size_t idx = (size_t)blockIdx.x * blockDim.x + threadIdx.x;
    size_t stride = (size_t)gridDim.x * blockDim.x;
    const size_t TOT = (size_t)TENC * N_ * IN_;
    for (size_t e = idx; e < TOT; e += stride) {
        int t = (int)(e / (N_ * IN_));
        int rem = (int)(e % (N_ * IN_));
        int n = rem / IN_, c = rem % IN_;
        xt2[e] = x[(size_t)n * 784 + c * TENC + t];
    }
    const size_t PW = (size_t)NTILE * N_;
    for (size_t e = idx; e < PW; e += stride) { sp0[e] = 0u; sp1[e] = 0u; }
    for (size_t e = idx; e < (size_t)PODS * FSTR; e += stride) flags[e] = 0u;
}

// ---------------------------------------------------------------------------
// Persistent LSNN, pod-local sync, TILE-MAJOR spike exchange (round-10 base)
// + PIPELINED staging: MFMA iteration c lands ONLY load k=c (strips 2c,2c+1)
// into LDS right before consuming it -> per-iteration vmcnt(12-c) instead of
// a full drain before the loop; loads c+1.. fly under MFMA(c). Only load 0's
// RTT is exposed. Sync/stores/numerics byte-identical to round 10.
// ---------------------------------------------------------------------------
__global__ __launch_bounds__(512)
__attribute__((amdgpu_waves_per_eu(2)))
void lsnn_persist(const float* __restrict__ xt2,
                  const float* __restrict__ Wi,
                  const float* __restrict__ b_i2h,
                  const float* __restrict__ Wh,
                  const float* __restrict__ b_h2h,
                  const float* __restrict__ Wo,
                  const float* __restrict__ b_h2o,
                  const float* __restrict__ tau_h,
                  const float* __restrict__ tau_o,
                  uint32_t* sp0, uint32_t* sp1,
                  uint32_t* flags,
                  float* __restrict__ out)
{
    extern __shared__ __align__(16) int8_t smem[];
    int8_t*   Bl  = smem;                                   // [NSEG][64][16]
    float*    wl  = (float*)(smem + SMEM_B);                // [28][32]
    uint32_t* Alds = (uint32_t*)(smem + SMEM_B + SMEM_W);   // [8 waves][32][AROW]

    const int bid  = blockIdx.x;
    const int pod  = bid / PBLK;          // 0..7 (sample group)
    const int l    = bid % PBLK;          // 0..25 (25 = o-block)
    const bool is_o = (l == 25);
    const int it   = is_o ? 0 : l;
    const int i0   = it * 32;
    const int wv   = threadIdx.x >> 6;
    const int lane = threadIdx.x & 63;
    const int quad = lane >> 4;
    const int col  = lane & 15;
    const int n0   = pod * 256 + wv * 32;
    uint32_t* ldsA = Alds + wv * 32 * AROW;
    const int dsel = (quad >> 1);
    const int dsh  = (quad & 1) * 16;

    // ---- build B digit fragments in LDS (once) ----
    for (int e = threadIdx.x; e < 13 * 2 * 64; e += 512) {
        int c  = e >> 7;
        int bh = (e >> 6) & 1;
        int ln = e & 63;
        int q  = ln >> 4, cl = ln & 15;
        int kbase = c * 64 + q * 16;
        uint32_t w4[4][4] = {};
        int row = bh * 16 + cl;
        #pragma unroll
        for (int j = 0; j < 16; ++j) {
            int kidx = kbase + j;
            float w = 0.f;
            if (kidx < H_) {
                if (!is_o) w = Wh[(size_t)(i0 + row) * H_ + kidx];
                else if (bh == 0 && cl < ONUM) w = Wo[(size_t)cl * H_ + kidx];
            }
            int8_t d[4]; digitize(w, d);
            #pragma unroll
            for (int k = 0; k < 4; ++k)
                w4[k][j >> 2] |= ((uint32_t)(uint8_t)d[k]) << ((j & 3) * 8);
        }
        #pragma unroll
        for (int k = 0; k < 4; ++k) {
            v4i v; v[0] = (int)w4[k][0]; v[1] = (int)w4[k][1];
            v[2] = (int)w4[k][2]; v[3] = (int)w4[k][3];
            *(v4i*)(Bl + (((c * 8) + k * 2 + bh) << 10) + (ln << 4)) = v;
        }
    }
    if (!is_o) {
        for (int e = threadIdx.x; e < IN_ * 32; e += 512) {
            int c = e >> 5, il = e & 31;
            wl[c * 32 + il] = Wi[(size_t)(i0 + il) * IN_ + c];
        }
    }
    // zero this wave's permanent K-pad column (strip 25 cells), written nowhere else
    if (lane >= 32) ldsA[(lane & 31) * AROW + 25] = 0u;

    // ---- constants & register state ----
    const float alpha = (float)exp((double)(-1.0f / 20.0f));
    const float onem  = 1.0f - alpha;
    const double INV32 = 1.0 / 4294967296.0;

    float roB[2] = {}, biB[2] = {}, bhB[2] = {};
    float hm[2][2][4] = {}, hbv[2][2][4];
    float om[2][4] = {}, ospv[2][4] = {}, obb[2][4], cnt[2][4] = {};
    float roO = 0.f, boO = 0.f;
    uint32_t pmask = 0;   // prev spikes for this lane's 16 outputs

    if (!is_o) {
        #pragma unroll
        for (int b = 0; b < 2; ++b) {
            int i = i0 + b * 16 + col;
            float arg = -1.0f / tau_h[i];
            roB[b] = (float)exp((double)arg);
            biB[b] = b_i2h[i]; bhB[b] = b_h2h[i];
        }
        #pragma unroll
        for (int a = 0; a < 2; ++a)
            #pragma unroll
            for (int b = 0; b < 2; ++b)
                #pragma unroll
                for (int r = 0; r < 4; ++r) hbv[a][b][r] = 0.01f;
    } else {
        if (col < ONUM) {
            float arg = -1.0f / tau_o[col];
            roO = (float)exp((double)arg);
            boO = b_h2o[col];
        }
        #pragma unroll
        for (int a = 0; a < 2; ++a)
            #pragma unroll
            for (int r = 0; r < 4; ++r) obb[a][r] = 0.01f;
    }

    // ---- per-lane staging geometry (constant across time) ----
    // load k: strip 2k + (lane>>5), row n0 + (lane&31); k=12 only lanes<32
    // (strip 25 is the permanent zero pad -> never loaded).
    uint32_t goff[13]; int loffv[13];
    #pragma unroll
    for (int k = 0; k < 13; ++k) {
        int tile = 2 * k + (lane >> 5);
        goff[k]  = (uint32_t)(tile * N_ + n0 + (lane & 31));
        loffv[k] = (lane & 31) * AROW + tile;
    }
    // qword spike-store gather: lane p<16 stores rows 2p,2p+1.
    const int j0 = (lane & 15) * 2;
    const int j1 = j0 + 1;
    const int s0 = ((j0 >> 2) & 3) * 16 + ((j0 >> 4) << 2) + (j0 & 3);
    const int s1 = ((j1 >> 2) & 3) * 16 + ((j1 >> 4) << 2) + (j1 & 3);

    __syncthreads();
    uint32_t epoch = 1;

    // ---- time loop ----
    for (int t = 0; t <= TTOT; ++t) {
        const uint32_t* rdP = (t & 1) ? sp1 : sp0;
        uint32_t*       wrP = (t & 1) ? sp0 : sp1;

        const bool active = is_o ? (t >= 1) : (t < TTOT);

        // ---- issue all staged loads into registers (landed per-c below) ----
        uint32_t vv[13];
        if (active) {
            #pragma unroll
            for (int k = 0; k < 13; ++k) {
                const bool real = (k < 12) || (lane < 32);
                vv[k] = real ? __hip_atomic_load(rdP + goff[k],
                            __ATOMIC_RELAXED, __HIP_MEMORY_SCOPE_AGENT) : 0u;
            }
        }

        // ---- input projection (spike-independent): overlaps load latency ----
        float inpf[2][2][4] = {};
        if (!is_o && active && t < TENC) {
            #pragma unroll
            for (int a = 0; a < 2; ++a) {
                #pragma unroll
                for (int r = 0; r < 4; ++r) {
                    int n = n0 + a * 16 + quad * 4 + r;
                    const float* xp = xt2 + ((size_t)t * N_ + n) * IN_;
                    double s0d = 0.0, s1d = 0.0;
                    #pragma unroll
                    for (int c = 0; c < IN_; ++c) {
                        double xv = (double)xp[c];
                        s0d += xv * (double)wl[c * 32 + col];
                        s1d += xv * (double)wl[c * 32 + 16 + col];
                    }
                    inpf[a][0][r] = (float)s0d;
                    inpf[a][1][r] = (float)s1d;
                }
            }
        }

        if (!is_o && active) {
            // PIPELINED: land load c, then MFMA on strips 2c,2c+1 while
            // loads c+1..12 remain in flight (per-iter vmcnt, not a drain).
            v4i acc4[2][2][4] = {};
            #pragma unroll
            for (int c = 0; c < 13; ++c) {
                const bool real = (c < 12) || (lane < 32);
                if (real) ldsA[loffv[c]] = vv[c];
                uint32_t d0 = ldsA[col * AROW + c * 2 + dsel];
                uint32_t d1 = ldsA[(16 + col) * AROW + c * 2 + dsel];
                v4i a0 = unpack16((d0 >> dsh) & 0xFFFFu);
                v4i a1 = unpack16((d1 >> dsh) & 0xFFFFu);
                #pragma unroll
                for (int k = 0; k < 4; ++k) {
                    v4i b0 = *(const v4i*)(Bl + (((c * 8) + k * 2 + 0) << 10) + (lane << 4));
                    v4i b1 = *(const v4i*)(Bl + (((c * 8) + k * 2 + 1) << 10) + (lane << 4));
                    acc4[0][0][k] = __builtin_amdgcn_mfma_i32_16x16x64_i8(a0, b0, acc4[0][0][k], 0, 0, 0);
                    acc4[0][1][k] = __builtin_amdgcn_mfma_i32_16x16x64_i8(a0, b1, acc4[0][1][k], 0, 0, 0);
                    acc4[1][0][k] = __builtin_amdgcn_mfma_i32_16x16x64_i8(a1, b0, acc4[1][0][k], 0, 0, 0);
                    acc4[1][1][k] = __builtin_amdgcn_mfma_i32_16x16x64_i8(a1, b1, acc4[1][1][k], 0, 0, 0);
                }
            }

            // hidden epilogue: fp32, reference order, no FMA; state in registers
            uint32_t nmask = 0;
            {
                #pragma clang fp contract(off)
                #pragma unroll
                for (int a = 0; a < 2; ++a) {
                    #pragma unroll
                    for (int b = 0; b < 2; ++b) {
                        #pragma unroll
                        for (int r = 0; r < 4; ++r) {
                            int sidx = ((a * 2 + b) * 4 + r);
                            int64_t tot = ((int64_t)acc4[a][b][3][r] << 24)
                                        + ((int64_t)acc4[a][b][2][r] << 16)
                                        + ((int64_t)acc4[a][b][1][r] << 8)
                                        +  (int64_t)acc4[a][b][0][r];
                            float rec = (float)((double)tot * INV32);
                            float h_in = ((inpf[a][b][r] + biB[b]) + rec) + bhB[b];
                            float sp = (pmask >> sidx) & 1u ? 1.0f : 0.0f;
                            float ro = roB[b];
                            float bnew = (ro * hbv[a][b][r]) + ((1.0f - ro) * sp);
                            float B = 0.01f + (1.8f * bnew);
                            float mem = ((hm[a][b][r] * alpha) + (onem * h_in)) - (B * sp);
                            float s = (mem - B) > 0.f ? 1.f : 0.f;
                            hbv[a][b][r] = bnew; hm[a][b][r] = mem;
                            if (s > 0.5f) nmask |= (1u << sidx);
                        }
                    }
                }
            }
            pmask = nmask;

            // pack spikes: ballots -> holder lanes; gather rows 2p,2p+1 into
            // lane p<16; ONE contiguous 128B segment as 16 x 8B sc1 stores.
            uint32_t wmine = 0;
            #pragma unroll
            for (int a = 0; a < 2; ++a) {
                #pragma unroll
                for (int r = 0; r < 4; ++r) {
                    unsigned long long bal0 = __ballot((nmask >> (a * 8 + r)) & 1u);
                    unsigned long long bal1 = __ballot((nmask >> (a * 8 + 4 + r)) & 1u);
                    if (col == a * 4 + r) {
                        wmine = (uint32_t)((bal0 >> (quad * 16)) & 0xFFFFull)
                              | ((uint32_t)((bal1 >> (quad * 16)) & 0xFFFFull) << 16);
                    }
                }
            }
            {
                uint32_t g0 = (uint32_t)__shfl((int)wmine, s0, 64);
                uint32_t g1 = (uint32_t)__shfl((int)wmine, s1, 64);
                if (lane < 16) {
                    uint64_t q = (uint64_t)g0 | ((uint64_t)g1 << 32);
                    uint64_t* qp = (uint64_t*)(wrP + (size_t)it * N_ + n0);
                    __hip_atomic_store(qp + (lane & 15), q,
                                       __ATOMIC_RELAXED, __HIP_MEMORY_SCOPE_AGENT);
                }
            }
        }

        if (is_o && active) {
            v4i oacc[2][4] = {};
            #pragma unroll
            for (int c = 0; c < 13; ++c) {
                const bool real = (c < 12) || (lane < 32);
                if (real) ldsA[loffv[c]] = vv[c];
                uint32_t d0 = ldsA[col * AROW + c * 2 + dsel];
                uint32_t d1 = ldsA[(16 + col) * AROW + c * 2 + dsel];
                v4i a0 = unpack16((d0 >> dsh) & 0xFFFFu);
                v4i a1 = unpack16((d1 >> dsh) & 0xFFFFu);
                #pragma unroll
                for (int k = 0; k < 4; ++k) {
                    v4i bo = *(const v4i*)(Bl + (((c * 8) + k * 2 + 0) << 10) + (lane << 4));
                    oacc[0][k] = __builtin_amdgcn_mfma_i32_16x16x64_i8(a0, bo, oacc[0][k], 0, 0, 0);
                    oacc[1][k] = __builtin_amdgcn_mfma_i32_16x16x64_i8(a1, bo, oacc[1][k], 0, 0, 0);
                }
            }
            if (col < ONUM) {
                #pragma clang fp contract(off)
                const bool msk = (t - 1) >= TENC;
                #pragma unroll
                for (int a = 0; a < 2; ++a) {
                    #pragma unroll
                    for (int r = 0; r < 4; ++r) {
                        int64_t tot = ((int64_t)oacc[a][3][r] << 24)
                                    + ((int64_t)oacc[a][2][r] << 16)
                                    + ((int64_t)oacc[a][1][r] << 8)
                                    +  (int64_t)oacc[a][0][r];
                        float o_in = ((float)((double)tot * INV32)) + boO;
                        float osp_ = ospv[a][r];
                        float bnew = (roO * obb[a][r]) + ((1.0f - roO) * osp_);
                        float B = 0.01f + (1.8f * bnew);
                        float mem = ((om[a][r] * alpha) + (onem * o_in)) - (B * osp_);
                        float s = (mem - B) > 0.f ? 1.f : 0.f;
                        obb[a][r] = bnew; om[a][r] = mem; ospv[a][r] = s;
                        if (msk) cnt[a][r] += s;
                    }
                }
            }
        }

        if (t < TTOT) pod_barrier(flags, pod, l, epoch++);
    }

    // ---- write spike counts ----
    if (is_o && col < ONUM) {
        #pragma unroll
        for (int a = 0; a < 2; ++a)
            #pragma unroll
            for (int r = 0; r < 4; ++r) {
                int n = n0 + a * 16 + quad * 4 + r;
                out[(size_t)n * ONUM + col] = cnt[a][r];
            }
    }
}

// ---------------------------------------------------------------------------
extern "C" void kernel_launch(void* const* d_in, const int* in_sizes, int n_in,
                              void* d_out, int out_size, void* d_ws, size_t ws_size,
                              hipStream_t stream)
{
    const float* x      = (const float*)d_in[0];
    const float* Wi     = (const float*)d_in[1];
    const float* b_i2h  = (const float*)d_in[2];
    const float* Wh     = (const float*)d_in[3];
    const float* b_h2h  = (const float*)d_in[4];
    const float* Wo     = (const float*)d_in[5];
    const float* b_h2o  = (const float*)d_in[6];
    const float* tau_h  = (const float*)d_in[7];
    const float* tau_o  = (const float*)d_in[8];
    float* out = (float*)d_out;

    uintptr_t p = (uintptr_t)d_ws;
    auto alloc = [&](size_t bytes) -> void* {
        p = (p + 255) & ~(uintptr_t)255;
        void* r = (void*)p; p += bytes; return r;
    };
    uint32_t* sp0   = (uint32_t*)alloc((size_t)NTILE * N_ * 4);
    uint32_t* sp1   = (uint32_t*)alloc((size_t)NTILE * N_ * 4);
    float*    xt2   = (float*)alloc((size_t)TENC * N_ * IN_ * 4);
    uint32_t* flags = (uint32_t*)alloc((size_t)PODS * FSTR * 4);

    prep_kernel<<<1024, 256, 0, stream>>>(x, xt2, sp0, sp1, flags);

    (void)hipFuncSetAttribute((const void*)lsnn_persist,
                              hipFuncAttributeMaxDynamicSharedMemorySize, SMEM_TOT);
    lsnn_persist<<<NBLK, 512, SMEM_TOT, stream>>>(
        xt2, Wi, b_i2h, Wh, b_h2h, Wo, b_h2o, tau_h, tau_o,
        sp0, sp1, flags, out);
}

// Round 13
// 1239.068 us; speedup vs baseline: 1.3649x; 1.1293x over previous
//
#include <hip/hip_runtime.h>
#include <math.h>
#include <stdint.h>

namespace {
constexpr int N_    = 2048;
constexpr int H_    = 800;
constexpr int IN_   = 28;
constexpr int TENC  = 28;
constexpr int TTOT  = 78;             // 28 encode + 50 decode
constexpr int ONUM  = 10;
constexpr int PODS  = 8;              // independent 256-sample pods
constexpr int PBLK  = 26;             // 25 hidden tiles + 1 output block per pod
constexpr int NBLK  = PODS * PBLK;    // 208
constexpr int NTILE = 26;             // spike strips: 25 real tiles + 1 zero K-pad
constexpr int BUFD  = NTILE * N_ + 2048;  // buffer stride (dwords) + 8KB prefetch guard
constexpr int NBUF  = TTOT + 1;       // 79 rotating buffers (writes go to t+1 <= 78)
constexpr int FSTR  = 32;             // flag dwords per pod (26 used -> 2 lines)
constexpr int NSEG  = 13 * 4 * 2;     // (c, digit k, neuron-half) B segments
constexpr int SMEM_B = NSEG * 1024;          // 106496: fragment-ordered digit planes
constexpr int SMEM_W = IN_ * 32 * 4;         // 3584: Wi tile
constexpr int AROW  = 27;                    // LDS A-strip row stride (dwords)
constexpr int SMEM_A = 8 * 32 * AROW * 4;    // 27648: per-wave A strips
constexpr int SMEM_TOT = SMEM_B + SMEM_W + SMEM_A;  // 137728 <= 160K -> 1 blk/CU
}

typedef __attribute__((ext_vector_type(4))) int v4i;

// balanced base-256 digits of round(w * 2^32); exact for |w| < ~0.49
__device__ __forceinline__ void digitize(float w, int8_t d[4]) {
    double dd = (double)w * 4294967296.0;
    long long r = (long long)rint(dd);
    int8_t d0 = (int8_t)(r & 255); r = (r - (long long)d0) >> 8;
    int8_t d1 = (int8_t)(r & 255); r = (r - (long long)d1) >> 8;
    int8_t d2 = (int8_t)(r & 255); r = (r - (long long)d2) >> 8;
    long long r3 = r; r3 = r3 > 127 ? 127 : (r3 < -128 ? -128 : r3);
    d[0] = d0; d[1] = d1; d[2] = d2; d[3] = (int8_t)r3;
}

// expand 16 spike bits -> 16 bytes (0/1) as v4i
__device__ __forceinline__ v4i unpack16(uint32_t u) {
    v4i f;
    f[0] = (int)((((u      ) & 0xFu) * 0x00204081u) & 0x01010101u);
    f[1] = (int)((((u >>  4) & 0xFu) * 0x00204081u) & 0x01010101u);
    f[2] = (int)((((u >>  8) & 0xFu) * 0x00204081u) & 0x01010101u);
    f[3] = (int)((((u >> 12) & 0xFu) * 0x00204081u) & 0x01010101u);
    return f;
}

// ---- pod-local grid barrier: 26 blocks, packed flag lines (2/pod) ---------
__device__ __forceinline__ void pod_barrier(uint32_t* __restrict__ flags,
                                            int pod, int l, uint32_t epoch) {
    __syncthreads();
    if (threadIdx.x < 64) {
        if (threadIdx.x == 0) {
            asm volatile("s_waitcnt vmcnt(0)" ::: "memory");
            __hip_atomic_store(flags + pod * FSTR + l, epoch,
                               __ATOMIC_RELAXED, __HIP_MEMORY_SCOPE_AGENT);
        }
        const bool mine = (threadIdx.x < PBLK);
        bool done = false;
        int itc = 0;
        while (!done) {
            bool ok = true;
            if (mine)
                ok = (__hip_atomic_load(flags + pod * FSTR + threadIdx.x,
                        __ATOMIC_RELAXED, __HIP_MEMORY_SCOPE_AGENT) >= epoch);
            done = (__ballot(ok) == ~0ull);
            if (!done) {
                if (itc < 4) __builtin_amdgcn_s_sleep(1);
                else         __builtin_amdgcn_s_sleep(8);
                ++itc;
            }
        }
    }
    __syncthreads();
}

// ---------------------------------------------------------------------------
// prepass: transpose x into xt2[t][n][c]; zero the first two spike buffers
// (buf0 = t=0 input; buf1 zeroed only for the 2-buffer fallback) + flags
// ---------------------------------------------------------------------------
__global__ void prep_kernel(const float* __restrict__ x, float* __restrict__ xt2,
                            uint32_t* __restrict__ spB, uint32_t* __restrict__ flags)
{
    size_t idx = (size_t)blockIdx.x * blockDim.x + threadIdx.x;
    size_t stride = (size_t)gridDim.x * blockDim.x;
    const size_t TOT = (size_t)TENC * N_ * IN_;
    for (size_t e = idx; e < TOT; e += stride) {
        int t = (int)(e / (N_ * IN_));
        int rem = (int)(e % (N_ * IN_));
        int n = rem / IN_, c = rem % IN_;
        xt2[e] = x[(size_t)n * 784 + c * TENC + t];
    }
    const size_t PW = (size_t)2 * BUFD;
    for (size_t e = idx; e < PW; e += stride) spB[e] = 0u;
    for (size_t e = idx; e < (size_t)PODS * FSTR; e += stride) flags[e] = 0u;
}

// ---------------------------------------------------------------------------
// Persistent LSNN, pod-local sync, TILE-MAJOR spikes, ROTATING FRESH BUFFERS:
//   step t reads buf[t], writes buf[t+1] (79 buffers, never reused within a
//   launch). Consumer lines are therefore never stale -> staged reads use
//   WORKGROUP-scope cacheable loads with NO fence: first toucher per 128B
//   line per XCD pays the MALL trip, the other ~25 blocks hit XCD L2.
//   Cross-launch freshness: kernel-dispatch acquire invalidates L1/L2 (the
//   same guarantee prep->main visibility already relies on). Producers keep
//   the proven sc1 qword stores + vmcnt drain + agent flags. If ws_size is
//   too small, nbuf=2 fallback reproduces round-10 exactly (agent loads).
// ---------------------------------------------------------------------------
__global__ __launch_bounds__(512)
__attribute__((amdgpu_waves_per_eu(2)))
void lsnn_persist(const float* __restrict__ xt2,
                  const float* __restrict__ Wi,
                  const float* __restrict__ b_i2h,
                  const float* __restrict__ Wh,
                  const float* __restrict__ b_h2h,
                  const float* __restrict__ Wo,
                  const float* __restrict__ b_h2o,
                  const float* __restrict__ tau_h,
                  const float* __restrict__ tau_o,
                  uint32_t* spB, int nbuf,
                  uint32_t* flags,
                  float* __restrict__ out)
{
    extern __shared__ __align__(16) int8_t smem[];
    int8_t*   Bl  = smem;                                   // [NSEG][64][16]
    float*    wl  = (float*)(smem + SMEM_B);                // [28][32]
    uint32_t* Alds = (uint32_t*)(smem + SMEM_B + SMEM_W);   // [8 waves][32][AROW]

    const int bid  = blockIdx.x;
    const int pod  = bid / PBLK;          // 0..7 (sample group)
    const int l    = bid % PBLK;          // 0..25 (25 = o-block)
    const bool is_o = (l == 25);
    const int it   = is_o ? 0 : l;
    const int i0   = it * 32;
    const int wv   = threadIdx.x >> 6;
    const int lane = threadIdx.x & 63;
    const int quad = lane >> 4;
    const int col  = lane & 15;
    const int n0   = pod * 256 + wv * 32;
    uint32_t* ldsA = Alds + wv * 32 * AROW;
    const int dsel = (quad >> 1);
    const int dsh  = (quad & 1) * 16;
    const bool fresh = (nbuf > 2);

    // ---- build B digit fragments in LDS (once) ----
    for (int e = threadIdx.x; e < 13 * 2 * 64; e += 512) {
        int c  = e >> 7;
        int bh = (e >> 6) & 1;
        int ln = e & 63;
        int q  = ln >> 4, cl = ln & 15;
        int kbase = c * 64 + q * 16;
        uint32_t w4[4][4] = {};
        int row = bh * 16 + cl;
        #pragma unroll
        for (int j = 0; j < 16; ++j) {
            int kidx = kbase + j;
            float w = 0.f;
            if (kidx < H_) {
                if (!is_o) w = Wh[(size_t)(i0 + row) * H_ + kidx];
                else if (bh == 0 && cl < ONUM) w = Wo[(size_t)cl * H_ + kidx];
            }
            int8_t d[4]; digitize(w, d);
            #pragma unroll
            for (int k = 0; k < 4; ++k)
                w4[k][j >> 2] |= ((uint32_t)(uint8_t)d[k]) << ((j & 3) * 8);
        }
        #pragma unroll
        for (int k = 0; k < 4; ++k) {
            v4i v; v[0] = (int)w4[k][0]; v[1] = (int)w4[k][1];
            v[2] = (int)w4[k][2]; v[3] = (int)w4[k][3];
            *(v4i*)(Bl + (((c * 8) + k * 2 + bh) << 10) + (ln << 4)) = v;
        }
    }
    if (!is_o) {
        for (int e = threadIdx.x; e < IN_ * 32; e += 512) {
            int c = e >> 5, il = e & 31;
            wl[c * 32 + il] = Wi[(size_t)(i0 + il) * IN_ + c];
        }
    }
    // zero this wave's permanent K-pad column (strip 25 cells), written nowhere else
    if (lane >= 32) ldsA[(lane & 31) * AROW + 25] = 0u;

    // ---- constants & register state ----
    const float alpha = (float)exp((double)(-1.0f / 20.0f));
    const float onem  = 1.0f - alpha;
    const double INV32 = 1.0 / 4294967296.0;

    float roB[2] = {}, biB[2] = {}, bhB[2] = {};
    float hm[2][2][4] = {}, hbv[2][2][4];
    float om[2][4] = {}, ospv[2][4] = {}, obb[2][4], cnt[2][4] = {};
    float roO = 0.f, boO = 0.f;
    uint32_t pmask = 0;   // prev spikes for this lane's 16 outputs

    if (!is_o) {
        #pragma unroll
        for (int b = 0; b < 2; ++b) {
            int i = i0 + b * 16 + col;
            float arg = -1.0f / tau_h[i];
            roB[b] = (float)exp((double)arg);
            biB[b] = b_i2h[i]; bhB[b] = b_h2h[i];
        }
        #pragma unroll
        for (int a = 0; a < 2; ++a)
            #pragma unroll
            for (int b = 0; b < 2; ++b)
                #pragma unroll
                for (int r = 0; r < 4; ++r) hbv[a][b][r] = 0.01f;
    } else {
        if (col < ONUM) {
            float arg = -1.0f / tau_o[col];
            roO = (float)exp((double)arg);
            boO = b_h2o[col];
        }
        #pragma unroll
        for (int a = 0; a < 2; ++a)
            #pragma unroll
            for (int r = 0; r < 4; ++r) obb[a][r] = 0.01f;
    }

    // ---- per-lane staging geometry (constant across time) ----
    // load k: strip 2k + (lane>>5), row n0 + (lane&31); k=12 only lanes<32
    // (strip 25 is the permanent zero pad -> never loaded).
    uint32_t goff[13]; int loffv[13];
    #pragma unroll
    for (int k = 0; k < 13; ++k) {
        int tile = 2 * k + (lane >> 5);
        goff[k]  = (uint32_t)(tile * N_ + n0 + (lane & 31));
        loffv[k] = (lane & 31) * AROW + tile;
    }
    // qword spike-store gather: lane p<16 stores rows 2p,2p+1.
    const int j0 = (lane & 15) * 2;
    const int j1 = j0 + 1;
    const int s0 = ((j0 >> 2) & 3) * 16 + ((j0 >> 4) << 2) + (j0 & 3);
    const int s1 = ((j1 >> 2) & 3) * 16 + ((j1 >> 4) << 2) + (j1 & 3);

    __syncthreads();
    uint32_t epoch = 1;

    // ---- time loop ----
    for (int t = 0; t <= TTOT; ++t) {
        const uint32_t* rdP = spB + (size_t)(t % nbuf) * BUFD;
        uint32_t*       wrP = spB + (size_t)((t + 1) % nbuf) * BUFD;

        const bool active = is_o ? (t >= 1) : (t < TTOT);

        // ---- issue staged loads into registers (latency overlapped below) ----
        uint32_t vv[13];
        if (active) {
            if (fresh) {
                #pragma unroll
                for (int k = 0; k < 13; ++k) {
                    const bool real = (k < 12) || (lane < 32);
                    vv[k] = real ? __hip_atomic_load(rdP + goff[k],
                                __ATOMIC_RELAXED, __HIP_MEMORY_SCOPE_WORKGROUP) : 0u;
                }
            } else {
                #pragma unroll
                for (int k = 0; k < 13; ++k) {
                    const bool real = (k < 12) || (lane < 32);
                    vv[k] = real ? __hip_atomic_load(rdP + goff[k],
                                __ATOMIC_RELAXED, __HIP_MEMORY_SCOPE_AGENT) : 0u;
                }
            }
        }

        // ---- input projection (spike-independent): overlaps load latency ----
        float inpf[2][2][4] = {};
        if (!is_o && active && t < TENC) {
            #pragma unroll
            for (int a = 0; a < 2; ++a) {
                #pragma unroll
                for (int r = 0; r < 4; ++r) {
                    int n = n0 + a * 16 + quad * 4 + r;
                    const float* xp = xt2 + ((size_t)t * N_ + n) * IN_;
                    double s0d = 0.0, s1d = 0.0;
                    #pragma unroll
                    for (int c = 0; c < IN_; ++c) {
                        double xv = (double)xp[c];
                        s0d += xv * (double)wl[c * 32 + col];
                        s1d += xv * (double)wl[c * 32 + 16 + col];
                    }
                    inpf[a][0][r] = (float)s0d;
                    inpf[a][1][r] = (float)s1d;
                }
            }
        }

        // ---- land staged words in this wave's A strip ----
        if (active) {
            #pragma unroll
            for (int k = 0; k < 13; ++k) {
                const bool real = (k < 12) || (lane < 32);
                if (real) ldsA[loffv[k]] = vv[k];
            }
        }

        if (!is_o && active) {
            v4i acc4[2][2][4] = {};
            #pragma unroll
            for (int c = 0; c < 13; ++c) {
                uint32_t d0 = ldsA[col * AROW + c * 2 + dsel];
                uint32_t d1 = ldsA[(16 + col) * AROW + c * 2 + dsel];
                v4i a0 = unpack16((d0 >> dsh) & 0xFFFFu);
                v4i a1 = unpack16((d1 >> dsh) & 0xFFFFu);
                #pragma unroll
                for (int k = 0; k < 4; ++k) {
                    v4i b0 = *(const v4i*)(Bl + (((c * 8) + k * 2 + 0) << 10) + (lane << 4));
                    v4i b1 = *(const v4i*)(Bl + (((c * 8) + k * 2 + 1) << 10) + (lane << 4));
                    acc4[0][0][k] = __builtin_amdgcn_mfma_i32_16x16x64_i8(a0, b0, acc4[0][0][k], 0, 0, 0);
                    acc4[0][1][k] = __builtin_amdgcn_mfma_i32_16x16x64_i8(a0, b1, acc4[0][1][k], 0, 0, 0);
                    acc4[1][0][k] = __builtin_amdgcn_mfma_i32_16x16x64_i8(a1, b0, acc4[1][0][k], 0, 0, 0);
                    acc4[1][1][k] = __builtin_amdgcn_mfma_i32_16x16x64_i8(a1, b1, acc4[1][1][k], 0, 0, 0);
                }
            }

            // hidden epilogue: fp32, reference order, no FMA; state in registers
            uint32_t nmask = 0;
            {
                #pragma clang fp contract(off)
                #pragma unroll
                for (int a = 0; a < 2; ++a) {
                    #pragma unroll
                    for (int b = 0; b < 2; ++b) {
                        #pragma unroll
                        for (int r = 0; r < 4; ++r) {
                            int sidx = ((a * 2 + b) * 4 + r);
                            int64_t tot = ((int64_t)acc4[a][b][3][r] << 24)
                                        + ((int64_t)acc4[a][b][2][r] << 16)
                                        + ((int64_t)acc4[a][b][1][r] << 8)
                                        +  (int64_t)acc4[a][b][0][r];
                            float rec = (float)((double)tot * INV32);
                            float h_in = ((inpf[a][b][r] + biB[b]) + rec) + bhB[b];
                            float sp = (pmask >> sidx) & 1u ? 1.0f : 0.0f;
                            float ro = roB[b];
                            float bnew = (ro * hbv[a][b][r]) + ((1.0f - ro) * sp);
                            float B = 0.01f + (1.8f * bnew);
                            float mem = ((hm[a][b][r] * alpha) + (onem * h_in)) - (B * sp);
                            float s = (mem - B) > 0.f ? 1.f : 0.f;
                            hbv[a][b][r] = bnew; hm[a][b][r] = mem;
                            if (s > 0.5f) nmask |= (1u << sidx);
                        }
                    }
                }
            }
            pmask = nmask;

            // pack spikes: ballots -> holder lanes; gather rows 2p,2p+1 into
            // lane p<16; ONE contiguous 128B segment as 16 x 8B sc1 stores.
            uint32_t wmine = 0;
            #pragma unroll
            for (int a = 0; a < 2; ++a) {
                #pragma unroll
                for (int r = 0; r < 4; ++r) {
                    unsigned long long bal0 = __ballot((nmask >> (a * 8 + r)) & 1u);
                    unsigned long long bal1 = __ballot((nmask >> (a * 8 + 4 + r)) & 1u);
                    if (col == a * 4 + r) {
                        wmine = (uint32_t)((bal0 >> (quad * 16)) & 0xFFFFull)
                              | ((uint32_t)((bal1 >> (quad * 16)) & 0xFFFFull) << 16);
                    }
                }
            }
            {
                uint32_t g0 = (uint32_t)__shfl((int)wmine, s0, 64);
                uint32_t g1 = (uint32_t)__shfl((int)wmine, s1, 64);
                if (lane < 16) {
                    uint64_t q = (uint64_t)g0 | ((uint64_t)g1 << 32);
                    uint64_t* qp = (uint64_t*)(wrP + (size_t)it * N_ + n0);
                    __hip_atomic_store(qp + (lane & 15), q,
                                       __ATOMIC_RELAXED, __HIP_MEMORY_SCOPE_AGENT);
                }
            }
        }

        if (is_o && active) {
            v4i oacc[2][4] = {};
            #pragma unroll
            for (int c = 0; c < 13; ++c) {
                uint32_t d0 = ldsA[col * AROW + c * 2 + dsel];
                uint32_t d1 = ldsA[(16 + col) * AROW + c * 2 + dsel];
                v4i a0 = unpack16((d0 >> dsh) & 0xFFFFu);
                v4i a1 = unpack16((d1 >> dsh) & 0xFFFFu);
                #pragma unroll
                for (int k = 0; k < 4; ++k) {
                    v4i bo = *(const v4i*)(Bl + (((c * 8) + k * 2 + 0) << 10) + (lane << 4));
                    oacc[0][k] = __builtin_amdgcn_mfma_i32_16x16x64_i8(a0, bo, oacc[0][k], 0, 0, 0);
                    oacc[1][k] = __builtin_amdgcn_mfma_i32_16x16x64_i8(a1, bo, oacc[1][k], 0, 0, 0);
                }
            }
            if (col < ONUM) {
                #pragma clang fp contract(off)
                const bool msk = (t - 1) >= TENC;
                #pragma unroll
                for (int a = 0; a < 2; ++a) {
                    #pragma unroll
                    for (int r = 0; r < 4; ++r) {
                        int64_t tot = ((int64_t)oacc[a][3][r] << 24)
                                    + ((int64_t)oacc[a][2][r] << 16)
                                    + ((int64_t)oacc[a][1][r] << 8)
                                    +  (int64_t)oacc[a][0][r];
                        float o_in = ((float)((double)tot * INV32)) + boO;
                        float osp_ = ospv[a][r];
                        float bnew = (roO * obb[a][r]) + ((1.0f - roO) * osp_);
                        float B = 0.01f + (1.8f * bnew);
                        float mem = ((om[a][r] * alpha) + (onem * o_in)) - (B * osp_);
                        float s = (mem - B) > 0.f ? 1.f : 0.f;
                        obb[a][r] = bnew; om[a][r] = mem; ospv[a][r] = s;
                        if (msk) cnt[a][r] += s;
                    }
                }
            }
        }

        if (t < TTOT) pod_barrier(flags, pod, l, epoch++);
    }

    // ---- write spike counts ----
    if (is_o && col < ONUM) {
        #pragma unroll
        for (int a = 0; a < 2; ++a)
            #pragma unroll
            for (int r = 0; r < 4; ++r) {
                int n = n0 + a * 16 + quad * 4 + r;
                out[(size_t)n * ONUM + col] = cnt[a][r];
            }
    }
}

// ---------------------------------------------------------------------------
extern "C" void kernel_launch(void* const* d_in, const int* in_sizes, int n_in,
                              void* d_out, int out_size, void* d_ws, size_t ws_size,
                              hipStream_t stream)
{
    const float* x      = (const float*)d_in[0];
    const float* Wi     = (const float*)d_in[1];
    const float* b_i2h  = (const float*)d_in[2];
    const float* Wh     = (const float*)d_in[3];
    const float* b_h2h  = (const float*)d_in[4];
    const float* Wo     = (const float*)d_in[5];
    const float* b_h2o  = (const float*)d_in[6];
    const float* tau_h  = (const float*)d_in[7];
    const float* tau_o  = (const float*)d_in[8];
    float* out = (float*)d_out;

    uintptr_t p = (uintptr_t)d_ws;
    auto alloc = [&](size_t bytes) -> void* {
        p = (p + 255) & ~(uintptr_t)255;
        void* r = (void*)p; p += bytes; return r;
    };
    float*    xt2   = (float*)alloc((size_t)TENC * N_ * IN_ * 4);   // 6.42 MB
    uint32_t* flags = (uint32_t*)alloc((size_t)PODS * FSTR * 4);

    // rotating fresh buffers if workspace allows; else round-10 2-buffer path
    uintptr_t used = (p + 255 & ~(uintptr_t)255) - (uintptr_t)d_ws;
    size_t bufbytes = (size_t)BUFD * 4;
    int nbuf = (ws_size >= used + (size_t)NBUF * bufbytes + 4096) ? NBUF : 2;
    uint32_t* spB = (uint32_t*)alloc((size_t)nbuf * bufbytes);

    prep_kernel<<<1024, 256, 0, stream>>>(x, xt2, spB, flags);

    (void)hipFuncSetAttribute((const void*)lsnn_persist,
                              hipFuncAttributeMaxDynamicSharedMemorySize, SMEM_TOT);
    lsnn_persist<<<NBLK, 512, SMEM_TOT, stream>>>(
        xt2, Wi, b_i2h, Wh, b_h2h, Wo, b_h2o, tau_h, tau_o,
        spB, nbuf, flags, out);
}

// Round 14
// 1168.271 us; speedup vs baseline: 1.4476x; 1.0606x over previous
//
#include <hip/hip_runtime.h>
#include <math.h>
#include <stdint.h>

namespace {
constexpr int N_    = 2048;
constexpr int H_    = 800;
constexpr int IN_   = 28;
constexpr int TENC  = 28;
constexpr int TTOT  = 78;             // 28 encode + 50 decode
constexpr int ONUM  = 10;
constexpr int PODS  = 8;              // independent 256-sample pods
constexpr int PBLK  = 26;             // 25 hidden tiles + 1 output block per pod
constexpr int NBLK  = PODS * PBLK;    // 208
constexpr int NTILE = 26;             // spike strips: 25 real + 1 pad slot (unused)
constexpr int BUFQ  = NTILE * N_ + 256;   // qwords per buffer + guard
constexpr int NBUF  = TTOT + 1;       // 79 rotating buffers: step t reads buf[t], writes buf[t+1]
constexpr int FSTR  = 32;             // flag dwords per pod (fallback barrier only)
constexpr int NSEG  = 13 * 4 * 2;     // (c, digit k, neuron-half) B segments
constexpr int SMEM_B = NSEG * 1024;          // 106496: fragment-ordered digit planes
constexpr int SMEM_W = IN_ * 32 * 4;         // 3584: Wi tile
constexpr int AROW  = 27;                    // LDS A-strip row stride (dwords)
constexpr int SMEM_A = 8 * 32 * AROW * 4;    // 27648: per-wave A strips
constexpr int SMEM_TOT = SMEM_B + SMEM_W + SMEM_A;  // 137728 <= 160K -> 1 blk/CU
}

typedef __attribute__((ext_vector_type(4))) int v4i;

// balanced base-256 digits of round(w * 2^32); exact for |w| < ~0.49
__device__ __forceinline__ void digitize(float w, int8_t d[4]) {
    double dd = (double)w * 4294967296.0;
    long long r = (long long)rint(dd);
    int8_t d0 = (int8_t)(r & 255); r = (r - (long long)d0) >> 8;
    int8_t d1 = (int8_t)(r & 255); r = (r - (long long)d1) >> 8;
    int8_t d2 = (int8_t)(r & 255); r = (r - (long long)d2) >> 8;
    long long r3 = r; r3 = r3 > 127 ? 127 : (r3 < -128 ? -128 : r3);
    d[0] = d0; d[1] = d1; d[2] = d2; d[3] = (int8_t)r3;
}

// expand 16 spike bits -> 16 bytes (0/1) as v4i
__device__ __forceinline__ v4i unpack16(uint32_t u) {
    v4i f;
    f[0] = (int)((((u      ) & 0xFu) * 0x00204081u) & 0x01010101u);
    f[1] = (int)((((u >>  4) & 0xFu) * 0x00204081u) & 0x01010101u);
    f[2] = (int)((((u >>  8) & 0xFu) * 0x00204081u) & 0x01010101u);
    f[3] = (int)((((u >> 12) & 0xFu) * 0x00204081u) & 0x01010101u);
    return f;
}

// ---- pod-local grid barrier (FALLBACK path only, proven round 10/13) ------
__device__ __forceinline__ void pod_barrier(uint32_t* __restrict__ flags,
                                            int pod, int l, uint32_t epoch) {
    __syncthreads();
    if (threadIdx.x < 64) {
        if (threadIdx.x == 0) {
            asm volatile("s_waitcnt vmcnt(0)" ::: "memory");
            __hip_atomic_store(flags + pod * FSTR + l, epoch,
                               __ATOMIC_RELAXED, __HIP_MEMORY_SCOPE_AGENT);
        }
        const bool mine = (threadIdx.x < PBLK);
        bool done = false;
        int itc = 0;
        while (!done) {
            bool ok = true;
            if (mine)
                ok = (__hip_atomic_load(flags + pod * FSTR + threadIdx.x,
                        __ATOMIC_RELAXED, __HIP_MEMORY_SCOPE_AGENT) >= epoch);
            done = (__ballot(ok) == ~0ull);
            if (!done) {
                if (itc < 4) __builtin_amdgcn_s_sleep(1);
                else         __builtin_amdgcn_s_sleep(8);
                ++itc;
            }
        }
    }
    __syncthreads();
}

// ---------------------------------------------------------------------------
// prepass: transpose x into xt2[t][n][c]; zero first two qword buffers
// (buf0: tag 0 == expected at t=0) + flags (fallback)
// ---------------------------------------------------------------------------
__global__ void prep_kernel(const float* __restrict__ x, float* __restrict__ xt2,
                            uint64_t* __restrict__ spB, uint32_t* __restrict__ flags)
{
    size_t idx = (size_t)blockIdx.x * blockDim.x + threadIdx.x;
    size_t stride = (size_t)gridDim.x * blockDim.x;
    const size_t TOT = (size_t)TENC * N_ * IN_;
    for (size_t e = idx; e < TOT; e += stride) {
        int t = (int)(e / (N_ * IN_));
        int rem = (int)(e % (N_ * IN_));
        int n = rem / IN_, c = rem % IN_;
        xt2[e] = x[(size_t)n * 784 + c * TENC + t];
    }
    const size_t PW = (size_t)2 * BUFQ;
    for (size_t e = idx; e < PW; e += stride) spB[e] = 0ull;
    for (size_t e = idx; e < (size_t)PODS * FSTR; e += stride) flags[e] = 0u;
}

// ---------------------------------------------------------------------------
// Persistent LSNN -- BARRIER-FREE forward dataflow (fresh path):
//   79 rotating qword buffers; step t reads buf[t], writes buf[t+1]; nothing
//   is ever overwritten. Each qword = {tag = t+1 (hi32) | 32 spike bits}:
//   the tag shares the 128B line with its data, so line freshness is
//   self-evident. Producers fire 32x8B sc1 stores and proceed (store flight
//   hides under next step's compute) -- NO drain, NO flags, NO syncthreads.
//   Consumers: 13 cacheable (workgroup-scope) loads, overlap fp64 input
//   projection, tag-check; late words retry via agent-scope loads (bypass
//   any stale L2 line) with bounded backoff. DEADLOCK-FREE BY TOPOLOGY:
//   dependency graph is a forward DAG rooted at prep-zeroed buf[0] (tag 0);
//   producers never block. Fallback (ws too small): round-13 barrier path.
// ---------------------------------------------------------------------------
__global__ __launch_bounds__(512)
__attribute__((amdgpu_waves_per_eu(2)))
void lsnn_persist(const float* __restrict__ xt2,
                  const float* __restrict__ Wi,
                  const float* __restrict__ b_i2h,
                  const float* __restrict__ Wh,
                  const float* __restrict__ b_h2h,
                  const float* __restrict__ Wo,
                  const float* __restrict__ b_h2o,
                  const float* __restrict__ tau_h,
                  const float* __restrict__ tau_o,
                  uint64_t* spB, int nbuf,
                  uint32_t* flags,
                  float* __restrict__ out)
{
    extern __shared__ __align__(16) int8_t smem[];
    int8_t*   Bl  = smem;                                   // [NSEG][64][16]
    float*    wl  = (float*)(smem + SMEM_B);                // [28][32]
    uint32_t* Alds = (uint32_t*)(smem + SMEM_B + SMEM_W);   // [8 waves][32][AROW]

    const int bid  = blockIdx.x;
    const int pod  = bid / PBLK;          // 0..7 (sample group)
    const int l    = bid % PBLK;          // 0..25 (25 = o-block)
    const bool is_o = (l == 25);
    const int it   = is_o ? 0 : l;
    const int i0   = it * 32;
    const int wv   = threadIdx.x >> 6;
    const int lane = threadIdx.x & 63;
    const int quad = lane >> 4;
    const int col  = lane & 15;
    const int n0   = pod * 256 + wv * 32;
    uint32_t* ldsA = Alds + wv * 32 * AROW;
    const int dsel = (quad >> 1);
    const int dsh  = (quad & 1) * 16;
    const bool fresh = (nbuf > 2);

    // ---- build B digit fragments in LDS (once) ----
    for (int e = threadIdx.x; e < 13 * 2 * 64; e += 512) {
        int c  = e >> 7;
        int bh = (e >> 6) & 1;
        int ln = e & 63;
        int q  = ln >> 4, cl = ln & 15;
        int kbase = c * 64 + q * 16;
        uint32_t w4[4][4] = {};
        int row = bh * 16 + cl;
        #pragma unroll
        for (int j = 0; j < 16; ++j) {
            int kidx = kbase + j;
            float w = 0.f;
            if (kidx < H_) {
                if (!is_o) w = Wh[(size_t)(i0 + row) * H_ + kidx];
                else if (bh == 0 && cl < ONUM) w = Wo[(size_t)cl * H_ + kidx];
            }
            int8_t d[4]; digitize(w, d);
            #pragma unroll
            for (int k = 0; k < 4; ++k)
                w4[k][j >> 2] |= ((uint32_t)(uint8_t)d[k]) << ((j & 3) * 8);
        }
        #pragma unroll
        for (int k = 0; k < 4; ++k) {
            v4i v; v[0] = (int)w4[k][0]; v[1] = (int)w4[k][1];
            v[2] = (int)w4[k][2]; v[3] = (int)w4[k][3];
            *(v4i*)(Bl + (((c * 8) + k * 2 + bh) << 10) + (ln << 4)) = v;
        }
    }
    if (!is_o) {
        for (int e = threadIdx.x; e < IN_ * 32; e += 512) {
            int c = e >> 5, il = e & 31;
            wl[c * 32 + il] = Wi[(size_t)(i0 + il) * IN_ + c];
        }
    }
    // zero this wave's permanent K-pad column (strip 25 cells), written nowhere else
    if (lane >= 32) ldsA[(lane & 31) * AROW + 25] = 0u;

    // ---- constants & register state ----
    const float alpha = (float)exp((double)(-1.0f / 20.0f));
    const float onem  = 1.0f - alpha;
    const double INV32 = 1.0 / 4294967296.0;

    float roB[2] = {}, biB[2] = {}, bhB[2] = {};
    float hm[2][2][4] = {}, hbv[2][2][4];
    float om[2][4] = {}, ospv[2][4] = {}, obb[2][4], cnt[2][4] = {};
    float roO = 0.f, boO = 0.f;
    uint32_t pmask = 0;   // prev spikes for this lane's 16 outputs

    if (!is_o) {
        #pragma unroll
        for (int b = 0; b < 2; ++b) {
            int i = i0 + b * 16 + col;
            float arg = -1.0f / tau_h[i];
            roB[b] = (float)exp((double)arg);
            biB[b] = b_i2h[i]; bhB[b] = b_h2h[i];
        }
        #pragma unroll
        for (int a = 0; a < 2; ++a)
            #pragma unroll
            for (int b = 0; b < 2; ++b)
                #pragma unroll
                for (int r = 0; r < 4; ++r) hbv[a][b][r] = 0.01f;
    } else {
        if (col < ONUM) {
            float arg = -1.0f / tau_o[col];
            roO = (float)exp((double)arg);
            boO = b_h2o[col];
        }
        #pragma unroll
        for (int a = 0; a < 2; ++a)
            #pragma unroll
            for (int r = 0; r < 4; ++r) obb[a][r] = 0.01f;
    }

    // ---- per-lane staging geometry (constant across time) ----
    // load k: strip 2k + (lane>>5), row n0 + (lane&31); k=12 only lanes<32.
    int goff[13]; int loffv[13];
    #pragma unroll
    for (int k = 0; k < 13; ++k) {
        int tile = 2 * k + (lane >> 5);
        goff[k]  = tile * N_ + n0 + (lane & 31);
        loffv[k] = (lane & 31) * AROW + tile;
    }
    // spike-store gather: lane p<32 stores row p's qword; the 32-bit word for
    // row j is held by lane ((j>>2)&3)*16 + (j>>4)*4 + (j&3).
    const int jrow = lane & 31;
    const int src  = ((jrow >> 2) & 3) * 16 + ((jrow >> 4) << 2) + (jrow & 3);

    __syncthreads();
    uint32_t epoch = 1;

    // ---- time loop (fresh path: NO barriers; waves free-run on tags) ----
    for (int t = 0; t <= TTOT; ++t) {
        const uint64_t* rdQ = spB + (size_t)(fresh ? t : (t & 1)) * BUFQ;
        uint64_t*       wrQ = spB + (size_t)(fresh ? (t + 1) : ((t + 1) & 1)) * BUFQ;

        const bool active = is_o ? (t >= 1) : (t < TTOT);

        // ---- issue staged loads (cacheable first-try on fresh path) ----
        uint64_t vv[13];
        if (active) {
            if (fresh) {
                #pragma unroll
                for (int k = 0; k < 13; ++k) {
                    const bool real = (k < 12) || (lane < 32);
                    vv[k] = real ? __hip_atomic_load(rdQ + goff[k],
                                __ATOMIC_RELAXED, __HIP_MEMORY_SCOPE_WORKGROUP) : 0ull;
                }
            } else {
                #pragma unroll
                for (int k = 0; k < 13; ++k) {
                    const bool real = (k < 12) || (lane < 32);
                    vv[k] = real ? __hip_atomic_load(rdQ + goff[k],
                                __ATOMIC_RELAXED, __HIP_MEMORY_SCOPE_AGENT) : 0ull;
                }
            }
        }

        // ---- input projection (spike-independent): overlaps load latency ----
        float inpf[2][2][4] = {};
        if (!is_o && active && t < TENC) {
            #pragma unroll
            for (int a = 0; a < 2; ++a) {
                #pragma unroll
                for (int r = 0; r < 4; ++r) {
                    int n = n0 + a * 16 + quad * 4 + r;
                    const float* xp = xt2 + ((size_t)t * N_ + n) * IN_;
                    double s0d = 0.0, s1d = 0.0;
                    #pragma unroll
                    for (int c = 0; c < IN_; ++c) {
                        double xv = (double)xp[c];
                        s0d += xv * (double)wl[c * 32 + col];
                        s1d += xv * (double)wl[c * 32 + 16 + col];
                    }
                    inpf[a][0][r] = (float)s0d;
                    inpf[a][1][r] = (float)s1d;
                }
            }
        }

        if (active) {
            // ---- fresh path: tag-verify; retry ONLY failing words via agent
            // scope (bypasses any stale L2 line). Tags monotone; producers
            // never block -> forward progress guaranteed.
            if (fresh) {
                int tries = 0;
                while (true) {
                    uint32_t fail = 0;
                    #pragma unroll
                    for (int k = 0; k < 13; ++k) {
                        const bool real = (k < 12) || (lane < 32);
                        if (real && (uint32_t)(vv[k] >> 32) != (uint32_t)t)
                            fail |= (1u << k);
                    }
                    if (__ballot(fail != 0) == 0ull) break;
                    if      (tries < 4)  __builtin_amdgcn_s_sleep(1);
                    else if (tries < 10) __builtin_amdgcn_s_sleep(4);
                    else                 __builtin_amdgcn_s_sleep(16);
                    ++tries;
                    #pragma unroll
                    for (int k = 0; k < 13; ++k) {
                        if (fail & (1u << k))
                            vv[k] = __hip_atomic_load(rdQ + goff[k],
                                        __ATOMIC_RELAXED, __HIP_MEMORY_SCOPE_AGENT);
                    }
                }
            }
            // ---- land staged words in this wave's A strip ----
            #pragma unroll
            for (int k = 0; k < 13; ++k) {
                const bool real = (k < 12) || (lane < 32);
                if (real) ldsA[loffv[k]] = (uint32_t)vv[k];
            }
        }

        if (!is_o && active) {
            v4i acc4[2][2][4] = {};
            #pragma unroll
            for (int c = 0; c < 13; ++c) {
                uint32_t d0 = ldsA[col * AROW + c * 2 + dsel];
                uint32_t d1 = ldsA[(16 + col) * AROW + c * 2 + dsel];
                v4i a0 = unpack16((d0 >> dsh) & 0xFFFFu);
                v4i a1 = unpack16((d1 >> dsh) & 0xFFFFu);
                #pragma unroll
                for (int k = 0; k < 4; ++k) {
                    v4i b0 = *(const v4i*)(Bl + (((c * 8) + k * 2 + 0) << 10) + (lane << 4));
                    v4i b1 = *(const v4i*)(Bl + (((c * 8) + k * 2 + 1) << 10) + (lane << 4));
                    acc4[0][0][k] = __builtin_amdgcn_mfma_i32_16x16x64_i8(a0, b0, acc4[0][0][k], 0, 0, 0);
                    acc4[0][1][k] = __builtin_amdgcn_mfma_i32_16x16x64_i8(a0, b1, acc4[0][1][k], 0, 0, 0);
                    acc4[1][0][k] = __builtin_amdgcn_mfma_i32_16x16x64_i8(a1, b0, acc4[1][0][k], 0, 0, 0);
                    acc4[1][1][k] = __builtin_amdgcn_mfma_i32_16x16x64_i8(a1, b1, acc4[1][1][k], 0, 0, 0);
                }
            }

            // hidden epilogue: fp32, reference order, no FMA; state in registers
            uint32_t nmask = 0;
            {
                #pragma clang fp contract(off)
                #pragma unroll
                for (int a = 0; a < 2; ++a) {
                    #pragma unroll
                    for (int b = 0; b < 2; ++b) {
                        #pragma unroll
                        for (int r = 0; r < 4; ++r) {
                            int sidx = ((a * 2 + b) * 4 + r);
                            int64_t tot = ((int64_t)acc4[a][b][3][r] << 24)
                                        + ((int64_t)acc4[a][b][2][r] << 16)
                                        + ((int64_t)acc4[a][b][1][r] << 8)
                                        +  (int64_t)acc4[a][b][0][r];
                            float rec = (float)((double)tot * INV32);
                            float h_in = ((inpf[a][b][r] + biB[b]) + rec) + bhB[b];
                            float sp = (pmask >> sidx) & 1u ? 1.0f : 0.0f;
                            float ro = roB[b];
                            float bnew = (ro * hbv[a][b][r]) + ((1.0f - ro) * sp);
                            float B = 0.01f + (1.8f * bnew);
                            float mem = ((hm[a][b][r] * alpha) + (onem * h_in)) - (B * sp);
                            float s = (mem - B) > 0.f ? 1.f : 0.f;
                            hbv[a][b][r] = bnew; hm[a][b][r] = mem;
                            if (s > 0.5f) nmask |= (1u << sidx);
                        }
                    }
                }
            }
            pmask = nmask;

            // pack spikes: ballots -> holder lanes; shfl row word to lane p<32;
            // store tagged qwords {t+1 | word}: 32 x 8B = ONE 256B segment.
            // Fire-and-forget (no drain): the tag IS the arrival signal.
            uint32_t wmine = 0;
            #pragma unroll
            for (int a = 0; a < 2; ++a) {
                #pragma unroll
                for (int r = 0; r < 4; ++r) {
                    unsigned long long bal0 = __ballot((nmask >> (a * 8 + r)) & 1u);
                    unsigned long long bal1 = __ballot((nmask >> (a * 8 + 4 + r)) & 1u);
                    if (col == a * 4 + r) {
                        wmine = (uint32_t)((bal0 >> (quad * 16)) & 0xFFFFull)
                              | ((uint32_t)((bal1 >> (quad * 16)) & 0xFFFFull) << 16);
                    }
                }
            }
            {
                uint32_t myw = (uint32_t)__shfl((int)wmine, src, 64);
                if (lane < 32) {
                    uint64_t q = ((uint64_t)(uint32_t)(t + 1) << 32) | (uint64_t)myw;
                    __hip_atomic_store(wrQ + (size_t)it * N_ + n0 + jrow, q,
                                       __ATOMIC_RELAXED, __HIP_MEMORY_SCOPE_AGENT);
                }
            }
        }

        if (is_o && active) {
            v4i oacc[2][4] = {};
            #pragma unroll
            for (int c = 0; c < 13; ++c) {
                uint32_t d0 = ldsA[col * AROW + c * 2 + dsel];
                uint32_t d1 = ldsA[(16 + col) * AROW + c * 2 + dsel];
                v4i a0 = unpack16((d0 >> dsh) & 0xFFFFu);
                v4i a1 = unpack16((d1 >> dsh) & 0xFFFFu);
                #pragma unroll
                for (int k = 0; k < 4; ++k) {
                    v4i bo = *(const v4i*)(Bl + (((c * 8) + k * 2 + 0) << 10) + (lane << 4));
                    oacc[0][k] = __builtin_amdgcn_mfma_i32_16x16x64_i8(a0, bo, oacc[0][k], 0, 0, 0);
                    oacc[1][k] = __builtin_amdgcn_mfma_i32_16x16x64_i8(a1, bo, oacc[1][k], 0, 0, 0);
                }
            }
            if (col < ONUM) {
                #pragma clang fp contract(off)
                const bool msk = (t - 1) >= TENC;
                #pragma unroll
                for (int a = 0; a < 2; ++a) {
                    #pragma unroll
                    for (int r = 0; r < 4; ++r) {
                        int64_t tot = ((int64_t)oacc[a][3][r] << 24)
                                    + ((int64_t)oacc[a][2][r] << 16)
                                    + ((int64_t)oacc[a][1][r] << 8)
                                    +  (int64_t)oacc[a][0][r];
                        float o_in = ((float)((double)tot * INV32)) + boO;
                        float osp_ = ospv[a][r];
                        float bnew = (roO * obb[a][r]) + ((1.0f - roO) * osp_);
                        float B = 0.01f + (1.8f * bnew);
                        float mem = ((om[a][r] * alpha) + (onem * o_in)) - (B * osp_);
                        float s = (mem - B) > 0.f ? 1.f : 0.f;
                        obb[a][r] = bnew; om[a][r] = mem; ospv[a][r] = s;
                        if (msk) cnt[a][r] += s;
                    }
                }
            }
        }

        if (!fresh && t < TTOT) pod_barrier(flags, pod, l, epoch++);
    }

    // ---- write spike counts ----
    if (is_o && col < ONUM) {
        #pragma unroll
        for (int a = 0; a < 2; ++a)
            #pragma unroll
            for (int r = 0; r < 4; ++r) {
                int n = n0 + a * 16 + quad * 4 + r;
                out[(size_t)n * ONUM + col] = cnt[a][r];
            }
    }
}

// ---------------------------------------------------------------------------
extern "C" void kernel_launch(void* const* d_in, const int* in_sizes, int n_in,
                              void* d_out, int out_size, void* d_ws, size_t ws_size,
                              hipStream_t stream)
{
    const float* x      = (const float*)d_in[0];
    const float* Wi     = (const float*)d_in[1];
    const float* b_i2h  = (const float*)d_in[2];
    const float* Wh     = (const float*)d_in[3];
    const float* b_h2h  = (const float*)d_in[4];
    const float* Wo     = (const float*)d_in[5];
    const float* b_h2o  = (const float*)d_in[6];
    const float* tau_h  = (const float*)d_in[7];
    const float* tau_o  = (const float*)d_in[8];
    float* out = (float*)d_out;

    uintptr_t p = (uintptr_t)d_ws;
    auto alloc = [&](size_t bytes) -> void* {
        p = (p + 255) & ~(uintptr_t)255;
        void* r = (void*)p; p += bytes; return r;
    };
    float*    xt2   = (float*)alloc((size_t)TENC * N_ * IN_ * 4);   // 6.42 MB
    uint32_t* flags = (uint32_t*)alloc((size_t)PODS * FSTR * 4);

    // rotating fresh qword buffers if workspace allows; else barrier fallback
    uintptr_t used = ((p + 255) & ~(uintptr_t)255) - (uintptr_t)d_ws;
    size_t bufbytes = (size_t)BUFQ * 8;
    int nbuf = (ws_size >= used + (size_t)NBUF * bufbytes + 4096) ? NBUF : 2;
    uint64_t* spB = (uint64_t*)alloc((size_t)nbuf * bufbytes);

    prep_kernel<<<1024, 256, 0, stream>>>(x, xt2, spB, flags);

    (void)hipFuncSetAttribute((const void*)lsnn_persist,
                              hipFuncAttributeMaxDynamicSharedMemorySize, SMEM_TOT);
    lsnn_persist<<<NBLK, 512, SMEM_TOT, stream>>>(
        xt2, Wi, b_i2h, Wh, b_h2h, Wo, b_h2o, tau_h, tau_o,
        spB, nbuf, flags, out);
}